// Round 12
// baseline (187.790 us; speedup 1.0000x reference)
//
#include <hip/hip_runtime.h>

// InternalInteraction: out[b,j,d] = sum_i [ relu((x_i*x_j)@W1^T + b1) @ W2^T + b2 ]
// Factored: hsum[b,j,h] = sum_i relu((x_i*x_j)@W1^T + b1); out = hsum@W2^T + 16*b2.
// B=2048, A=16, D=128, H=512. Storage fp32; MFMA in bf16.
//
// Round-15 structure (vs r8/r14 at 87.0us):
//  - OBSERVATION: r8 itself micro-spills (~3MB WRITE + ~1.5MB FETCH above
//    the pure-out/pure-x floor of 16.38/9.3MB) -> zero register slack.
//    Every +16-reg DPP vehicle (r9/r13) tipped this edge into 95-98MB.
//  - LIVENESS CUT: per-n epilogue. Each n's {MFMA chain -> relu ->
//    aligned add -> rotated bperm-add} completes before the next n's v
//    exists. Peak v liveness 16 regs -> ~4. The rotate/no-rotate branch
//    is hoisted AROUND the n-loop (duplicated bodies) so there is still
//    exactly one uniform branch per dlt and the af loads stay at the top
//    (r12 lesson: never put control flow between af loads and their use).
//  - VECTOR relu/add: __builtin_elementwise_max + whole-vector += on
//    f32x4 -> clang can emit v_pk_max_f32 / v_pk_add_f32 (VALU halved
//    on those ops; pipe model is additive so VALU cuts show on the wall).
//  - PURPOSE: verify slack creation via WRITE_SIZE -> 16.4MB. If confirmed,
//    next round spends the slack on the DPP-Horner (+16 regs) that removes
//    the 112 bpermute/wave LDS cost. If not confirmed, lock r8-class.
//  - Everything else = r8: 512 thr / 8 waves / 64 h per wave, (512,4),
//    9 shift tiles (symmetry cut), swapped-operand GEMM1 (C rows=h,
//    cols=j), unroll-1 dlt loop, f32 xs staging, hs aliasing dead ps.

#define BATCH 2048
#define AA 16
#define DD 128
#define HH 512

typedef __bf16 bf16;
typedef bf16  bf16x4 __attribute__((ext_vector_type(4)));
typedef bf16  bf16x8 __attribute__((ext_vector_type(8)));
typedef float f32x4  __attribute__((ext_vector_type(4)));

__device__ inline f32x4 splat4(float v) { f32x4 r = {v, v, v, v}; return r; }

// pull float from another lane: idx = source_lane * 4 (byte index)
__device__ inline float bperm_f32(int idx, float v) {
    return __int_as_float(__builtin_amdgcn_ds_bpermute(idx, __float_as_int(v)));
}

// ---- prologue: fp32 -> bf16 weight conversion into d_ws ----
// ws layout: [0, 65536)  = W1b (512x128 row-major bf16)
//            [65536, ..) = W2b (128x512 row-major bf16)
__global__ __launch_bounds__(256, 1)
void convert_weights(const float* __restrict__ W1,
                     const float* __restrict__ W2,
                     bf16* __restrict__ wsb)
{
    int t = blockIdx.x * 256 + threadIdx.x;      // 0..32767, 4 elems each
    f32x4 v = (t < 16384) ? *(const f32x4*)(W1 + 4 * t)
                          : *(const f32x4*)(W2 + 4 * (t - 16384));
    bf16x4 o;
    o[0] = (bf16)v[0]; o[1] = (bf16)v[1]; o[2] = (bf16)v[2]; o[3] = (bf16)v[3];
    *(bf16x4*)(wsb + 4 * t) = o;
}

// One block per batch. 512 threads = 8 waves; wave w owns H cols [w*64, w*64+64).
__global__ __launch_bounds__(512, 4)
void interact_kernel(const float* __restrict__ x,    // [B, A, D] fp32
                     const bf16*  __restrict__ W1b,  // [H, D] bf16 (from ws)
                     const float* __restrict__ b1,   // [H]
                     const bf16*  __restrict__ W2b,  // [D, H] bf16 (from ws)
                     const float* __restrict__ b2,   // [D]
                     float* __restrict__ out)        // [B, A, D] fp32
{
    // xs: x_b in f32, row stride 136 (544 B)
    __shared__ float xs[16][136];                               // 8704 B
    // ps: 9 shift-tiles [dlt][j][136] bf16; tile dlt row j = x_{(j+dlt)&15}*x_j.
    //     row stride 272 B -> frag b128 reads uniform over 8 bank-slots.
    // hs: GEMM2 staging [16][520] bf16 (16640 B) -- ALIASES ps (dead by then).
    __shared__ __align__(16) unsigned char smem_raw[9 * 16 * 136 * 2];  // 39168 B
    bf16 (*ps)[16][136] = reinterpret_cast<bf16(*)[16][136]>(smem_raw);
    bf16 (*hs)[520]     = reinterpret_cast<bf16(*)[520]>(smem_raw);

    const int b    = blockIdx.x;
    const int tid  = threadIdx.x;
    const int wave = tid >> 6;    // 0..7
    const int lane = tid & 63;
    const int quad = lane >> 4;   // 0..3
    const int col  = lane & 15;   // 0..15

    // build-phase coordinates: thread owns (jrow, dq..dq+4)
    const int jrow = tid >> 5;          // 0..15
    const int dq   = (tid & 31) * 4;    // 0..124

    // ---- stage x_b into LDS (f32); keep own 4-float slice in regs ----
    f32x4 xj;
    {
        const float* src = x + (size_t)b * (AA * DD) + jrow * DD + dq;
        xj = *(const f32x4*)src;
        *(f32x4*)(&xs[jrow][dq]) = xj;
    }

    // ---- W1 fragments, register-resident (4n x 4kk x 16B = 64 regs) ----
    // Used as MFMA arg0 (A-operand): lane holds W1b[h = n*16+col][k-slice].
    bf16x8 w1f[4][4];
    f32x4  bias4[4];   // C-seed: b1[h0 + quad*4 + r] per reg r (C rows = h)
#pragma unroll
    for (int n = 0; n < 4; ++n) {
        int h    = wave * 64 + n * 16 + col;
        bias4[n] = *(const f32x4*)(b1 + wave * 64 + n * 16 + quad * 4);
#pragma unroll
        for (int kk = 0; kk < 4; ++kk)
            w1f[n][kk] = *(const bf16x8*)(W1b + h * DD + kk * 32 + quad * 8);
    }

    f32x4 hsum[4];
#pragma unroll
    for (int n = 0; n < 4; ++n) hsum[n] = splat4(0.f);

    __syncthreads();   // xs complete

    // ---- build 9 shift tiles: ps[dlt][j][d] = bf16(x_{(j+dlt)&15}[d]*x_j[d]) ----
#pragma unroll
    for (int dlt = 0; dlt < 9; ++dlt) {
        f32x4 xi = *(f32x4*)(&xs[(jrow + dlt) & 15][dq]);
        bf16x4 pr;
#pragma unroll
        for (int e = 0; e < 4; ++e) pr[e] = (bf16)(xj[e] * xi[e]);
        *(bf16x4*)(&ps[dlt][jrow][dq]) = pr;
    }
    __syncthreads();   // all tiles ready; no barriers until GEMM2 staging

    // ---- GEMM1 over 9 shift tiles (SWAPPED operands: C rows=h, cols=j) ----
    // arg0 = w1f (A rows = h-sub = col), arg1 = af (B cols = j = col).
    // C/D: lane(q,c) holds v[h = base + n*16 + q*4 + r][j = c].
    // hsum[j] = sum_{d=0..8} v_d[j] + sum_{d=1..7} v_d[(j-d)&15]; the second
    // term is a pure lane-rotation within the 16-lane col group -> one
    // runtime-indexed ds_bpermute per (n,r). Per-n epilogue keeps only ONE
    // v (4 regs) at peak liveness; one uniform branch per dlt.
#pragma unroll 1
    for (int dlt = 0; dlt < 9; ++dlt) {
        bf16x8 af[4];
#pragma unroll
        for (int kk = 0; kk < 4; ++kk)
            af[kk] = *(bf16x8*)(&ps[dlt][col][kk * 32 + quad * 8]);

        if (dlt >= 1 && dlt <= 7) {
            const int idx = ((quad << 4) | ((col - dlt) & 15)) << 2;
#pragma unroll
            for (int n = 0; n < 4; ++n) {
                f32x4 v = __builtin_amdgcn_mfma_f32_16x16x32_bf16(
                    w1f[n][0], af[0], bias4[n], 0, 0, 0);
#pragma unroll
                for (int kk = 1; kk < 4; ++kk)
                    v = __builtin_amdgcn_mfma_f32_16x16x32_bf16(
                        w1f[n][kk], af[kk], v, 0, 0, 0);
                v = __builtin_elementwise_max(v, splat4(0.f));
                hsum[n] += v;                       // aligned add (vector)
#pragma unroll
                for (int r = 0; r < 4; ++r)         // rotated add (tile 16-dlt)
                    hsum[n][r] += bperm_f32(idx, v[r]);
            }
        } else {   // dlt = 0 (diagonal) and dlt = 8 (self-paired): add once
#pragma unroll
            for (int n = 0; n < 4; ++n) {
                f32x4 v = __builtin_amdgcn_mfma_f32_16x16x32_bf16(
                    w1f[n][0], af[0], bias4[n], 0, 0, 0);
#pragma unroll
                for (int kk = 1; kk < 4; ++kk)
                    v = __builtin_amdgcn_mfma_f32_16x16x32_bf16(
                        w1f[n][kk], af[kk], v, 0, 0, 0);
                v = __builtin_elementwise_max(v, splat4(0.f));
                hsum[n] += v;
            }
        }
    }

    __syncthreads();   // all ps reads done before hs overwrites the region

    // ---- hsum -> LDS (bf16) for GEMM2 A-operand re-layout ----
    // Transposed C layout: lane(q,c) holds hsum[j=c][h = w*64+n*16+q*4+r]
    // -> contiguous in h: one bf16x4 store per n.
#pragma unroll
    for (int n = 0; n < 4; ++n) {
        bf16x4 o;
#pragma unroll
        for (int r = 0; r < 4; ++r) o[r] = (bf16)hsum[n][r];
        *(bf16x4*)(&hs[col][wave * 64 + n * 16 + quad * 4]) = o;
    }

    __syncthreads();

    // ---- GEMM2: out[j,d] = hsum[j,:] @ W2^T + 16*b2 ----
    // M=16 (j), N=16 per wave (d = wave*16 + col), K=512 (h). W2b is [D,H].
    const int d = wave * 16 + col;
    f32x4 acc2 = splat4(16.f * b2[d]);

#pragma unroll
    for (int ks = 0; ks < 16; ++ks) {
        int h0 = ks * 32 + quad * 8;
        bf16x8 a2 = *(bf16x8*)(&hs[col][h0]);
        bf16x8 bw = *(const bf16x8*)(W2b + d * HH + h0);
        acc2 = __builtin_amdgcn_mfma_f32_16x16x32_bf16(a2, bw, acc2, 0, 0, 0);
    }

#pragma unroll
    for (int r = 0; r < 4; ++r) {
        int j = quad * 4 + r;
        out[(size_t)b * (AA * DD) + j * DD + d] = acc2[r];
    }
}

extern "C" void kernel_launch(void* const* d_in, const int* in_sizes, int n_in,
                              void* d_out, int out_size, void* d_ws, size_t ws_size,
                              hipStream_t stream)
{
    const float* x  = (const float*)d_in[0];  // [2048,16,128]
    const float* W1 = (const float*)d_in[1];  // [512,128]
    const float* b1 = (const float*)d_in[2];  // [512]
    const float* W2 = (const float*)d_in[3];  // [128,512]
    const float* b2 = (const float*)d_in[4];  // [128]
    float* out = (float*)d_out;

    bf16* wsb = (bf16*)d_ws;                  // 256 KB used
    convert_weights<<<128, 256, 0, stream>>>(W1, W2, wsb);

    const bf16* W1b = wsb;
    const bf16* W2b = wsb + (size_t)HH * DD;
    interact_kernel<<<BATCH, 512, 0, stream>>>(x, W1b, b1, W2b, b2, out);
}